// Round 9
// baseline (5282.687 us; speedup 1.0000x reference)
//
#include <hip/hip_runtime.h>
#include <math.h>

// Problem constants
#define BB 64
#define TT 512
#define II 512
#define HH 1024
#define OO 128
#define GN (3*HH)       // 3072
#define TC 64           // time chunk
#define NCH (TT/TC)     // 8 chunks
#define NSLOT 65        // rolling h slots (64 steps/dispatch < 65 => unique addrs)

using u16 = unsigned short;
typedef __attribute__((ext_vector_type(8))) short bf16x8;
typedef __attribute__((ext_vector_type(4))) float f32x4;
typedef __attribute__((ext_vector_type(4))) unsigned short u16x4;

__device__ __forceinline__ u16 f2bf(float f){
  unsigned u = __builtin_bit_cast(unsigned, f);
  u += 0x7fffu + ((u >> 16) & 1u);          // RNE
  return (u16)(u >> 16);
}
__device__ __forceinline__ float bf2f(u16 h){
  unsigned u = ((unsigned)h) << 16;
  return __builtin_bit_cast(float, u);
}

// ---------------------------------------------------------------- f32 -> bf16
__global__ __launch_bounds__(256) void cvt_kernel(const float* __restrict__ s,
                                                  u16* __restrict__ d, int n4){
  int stride = gridDim.x * 256;
  for (int i = blockIdx.x * 256 + threadIdx.x; i < n4; i += stride){
    float4 v = reinterpret_cast<const float4*>(s)[i];
    u16x4 o; o.x = f2bf(v.x); o.y = f2bf(v.y); o.z = f2bf(v.z); o.w = f2bf(v.w);
    reinterpret_cast<u16x4*>(d)[i] = o;
  }
}

// --------------------------------------------- x chunk gather+convert to bf16
__global__ __launch_bounds__(256) void cvtx_chunk(const float* __restrict__ x,
                                                  u16* __restrict__ d, int t0){
  const int per_b = TC * II / 4;
  int stride = gridDim.x * 256;
  for (int i = blockIdx.x * 256 + threadIdx.x; i < BB * per_b; i += stride){
    int b = i / per_b, r = i - b * per_b;
    float4 v = reinterpret_cast<const float4*>(x)[(size_t)(b * TT + t0) * (II/4) + r];
    u16x4 o; o.x = f2bf(v.x); o.y = f2bf(v.y); o.z = f2bf(v.z); o.w = f2bf(v.w);
    reinterpret_cast<u16x4*>(d)[(size_t)b * per_b + r] = o;
  }
}

// ------------------------------------------------- bf16 GEMM: C = A@Bw^T + bias
// m97 structure: 128x128 tile, BK=32, 4 waves, global_load_lds width 16.
template<int K>
__global__ __launch_bounds__(256) void gemm_bias(const u16* __restrict__ A,
    const u16* __restrict__ Bw, const float* __restrict__ bias, u16* __restrict__ C){
  __shared__ u16 As[128*32];
  __shared__ u16 Bs[128*32];
  int tid = threadIdx.x;
  int lane = tid & 63, wave = tid >> 6;
  int m0 = blockIdx.x * 128, n0 = blockIdx.y * 128;
  int wr = (wave >> 1) * 64, wc = (wave & 1) * 64;
  int fr = lane & 15, fo = (lane >> 4) * 8;
  f32x4 acc[4][4] = {};
  for (int k0 = 0; k0 < K; k0 += 32){
    __syncthreads();
    #pragma unroll
    for (int c = 0; c < 2; ++c){
      int chunk = wave * 2 + c;
      int s = chunk * 64 + lane;
      int row = s >> 2, o = s & 3;
      const u16* ga = A  + (size_t)(m0 + row) * K + k0 + o * 8;
      const u16* gb = Bw + (size_t)(n0 + row) * K + k0 + o * 8;
      __builtin_amdgcn_global_load_lds(
          (const __attribute__((address_space(1))) unsigned int*)ga,
          (__attribute__((address_space(3))) unsigned int*)(As + chunk * 512), 16, 0, 0);
      __builtin_amdgcn_global_load_lds(
          (const __attribute__((address_space(1))) unsigned int*)gb,
          (__attribute__((address_space(3))) unsigned int*)(Bs + chunk * 512), 16, 0, 0);
    }
    __syncthreads();
    bf16x8 af[4], bf[4];
    #pragma unroll
    for (int m = 0; m < 4; ++m)
      af[m] = *reinterpret_cast<const bf16x8*>(&As[(wr + m*16 + fr) * 32 + fo]);
    #pragma unroll
    for (int n = 0; n < 4; ++n)
      bf[n] = *reinterpret_cast<const bf16x8*>(&Bs[(wc + n*16 + fr) * 32 + fo]);
    #pragma unroll
    for (int m = 0; m < 4; ++m)
      #pragma unroll
      for (int n = 0; n < 4; ++n)
        acc[m][n] = __builtin_amdgcn_mfma_f32_16x16x32_bf16(af[m], bf[n], acc[m][n], 0, 0, 0);
  }
  int r4 = (lane >> 4) * 4;
  #pragma unroll
  for (int n = 0; n < 4; ++n){
    int col = n0 + wc + n*16 + fr;
    float bv = bias[col];
    #pragma unroll
    for (int m = 0; m < 4; ++m){
      #pragma unroll
      for (int q = 0; q < 4; ++q){
        int row = m0 + wr + m*16 + r4 + q;
        C[(size_t)row * GN + col] = f2bf(acc[m][n][q] + bv);
      }
    }
  }
}

// --------------------------------------------------- GRU chunk body (R9)
// Per role: 128 WGs x 128 threads = 2 batch-groups(32 rows) x 64 col-slices(16).
// Wave w owns batch rows [16w,16w+16) of its group x 16 cols x ALL 3 gates with
// FULL K=1024 (96 MFMA) -> no cross-wave reduce, NO barriers in the step loop.
// Memory protocol = R7 verbatim: rolling 65-slot hbuf; producer relaxed agent
// atomic 2B stores (LLC write-through) + per-WAVE vmcnt(0) drain + lane0 flag;
// consumer: 1 uncached 4B flag load/lane over 64 same-plane producers, then
// plain CACHED 16B h loads (first-touch per dispatch; dispatch-boundary acquire
// invalidates L2). Wave-plane isolation: consumer wave w only needs producer
// waves w. h1c/hstate stores issued AFTER the flag (off the critical path).
__device__ __forceinline__ void gru_chunk(
    const u16* __restrict__ gx, const u16* __restrict__ Whh, const float* __restrict__ bhh,
    u16* hbuf, unsigned* flags, u16* h1c, float* hstate, int base,
    int bl, u16* Ws)
{
  int tid = threadIdx.x, lane = tid & 63, w = tid >> 6;     // w in {0,1}
  int grp = bl >> 6, wg = bl & 63;
  int c0 = wg * 16, rb0 = grp * 32;
  // stage W slice: LDS row r = gate*16 + col_local, stride 1032 (pad)
  for (int ch = tid; ch < 48 * 128; ch += 128){
    int r = ch >> 7, o = ch & 127;
    const u16* src = Whh + (size_t)((r >> 4) * HH + c0 + (r & 15)) * HH + o * 8;
    *reinterpret_cast<int4*>(&Ws[r * 1032 + o * 8]) = *reinterpret_cast<const int4*>(src);
  }
  __syncthreads();                                          // once, outside the loop
  int fr = lane & 15, klo = (lane >> 4) * 8, r4 = (lane >> 4) * 4;
  int myrow0 = rb0 + w * 16;                                // wave's 16 batch rows
  float br = bhh[c0 + fr], bz = bhh[HH + c0 + fr], bn2 = bhh[2*HH + c0 + fr];
  // per-lane output rows: myrow0 + r4 + q  (q=0..3), col c0 + fr
  float ho[4];
  #pragma unroll
  for (int q = 0; q < 4; ++q)
    ho[q] = hstate[(size_t)(myrow0 + r4 + q) * HH + c0 + fr];
  // flags: per (grp, wg, wave), 64B padded
  unsigned* myflag = flags + ((grp * 64 + wg) * 2 + w) * 16;
  const unsigned* pollbase = flags + (grp * 64 + lane) * 2 * 16 + w * 16;
  for (int tl = 0; tl < TC; ++tl){
    int t = base + tl;
    // gx prefetch (h-independent): 12 scalar loads, issued before the wait
    float gr[4], gz[4], gn[4];
    #pragma unroll
    for (int q = 0; q < 4; ++q){
      const u16* gp = gx + (size_t)(myrow0 + r4 + q) * TC * GN + (size_t)tl * GN + c0 + fr;
      gr[q] = bf2f(gp[0]); gz[q] = bf2f(gp[HH]); gn[q] = bf2f(gp[2*HH]);
    }
    f32x4 accR = {}, accZ = {}, accN = {};
    if (t){
      unsigned want = (unsigned)t;
      for (;;){
        unsigned v = __hip_atomic_load(pollbase, __ATOMIC_RELAXED,
                                       __HIP_MEMORY_SCOPE_AGENT);
        if (__all((int)(v >= want))) break;
        __builtin_amdgcn_s_sleep(1);
      }
      asm volatile("" ::: "memory");   // keep h loads below the poll
      // h A-fragments: 32 cached 16B loads, row myrow0+fr, full K
      const u16* hr = hbuf + (size_t)((t - 1) % NSLOT) * (BB * HH)
                    + (size_t)(myrow0 + fr) * HH + klo;
      bf16x8 af[32];
      #pragma unroll
      for (int ks = 0; ks < 32; ++ks)
        af[ks] = *reinterpret_cast<const bf16x8*>(hr + ks * 32);
      #pragma unroll
      for (int ks = 0; ks < 32; ++ks){
        int kk = ks * 32 + klo;
        bf16x8 w0 = *reinterpret_cast<const bf16x8*>(&Ws[(     fr) * 1032 + kk]);
        bf16x8 w1 = *reinterpret_cast<const bf16x8*>(&Ws[(16 + fr) * 1032 + kk]);
        bf16x8 w2 = *reinterpret_cast<const bf16x8*>(&Ws[(32 + fr) * 1032 + kk]);
        accR = __builtin_amdgcn_mfma_f32_16x16x32_bf16(af[ks], w0, accR, 0, 0, 0);
        accZ = __builtin_amdgcn_mfma_f32_16x16x32_bf16(af[ks], w1, accZ, 0, 0, 0);
        accN = __builtin_amdgcn_mfma_f32_16x16x32_bf16(af[ks], w2, accN, 0, 0, 0);
      }
    }
    // gates: lane's D rows = r4+q, col = fr  [m89-verified D map]
    u16 hb[4]; float hn[4];
    #pragma unroll
    for (int q = 0; q < 4; ++q){
      float r_ = __builtin_amdgcn_rcpf(1.f + __expf(-(gr[q] + accR[q] + br)));
      float z_ = __builtin_amdgcn_rcpf(1.f + __expf(-(gz[q] + accZ[q] + bz)));
      float nx = gn[q] + r_ * (accN[q] + bn2);
      float n_ = 1.f - 2.f * __builtin_amdgcn_rcpf(__expf(2.f * nx) + 1.f);
      hn[q] = (1.f - z_) * n_ + z_ * ho[q];
      ho[q] = hn[q];                              // f32 self-path
      hb[q] = f2bf(hn[q]);
    }
    // publish: 4 atomic 2B stores into write slot, drain OWN wave, flag
    u16* wslot = hbuf + (size_t)(t % NSLOT) * (BB * HH);
    #pragma unroll
    for (int q = 0; q < 4; ++q)
      __hip_atomic_store(wslot + (size_t)(myrow0 + r4 + q) * HH + c0 + fr,
                         hb[q], __ATOMIC_RELAXED, __HIP_MEMORY_SCOPE_AGENT);
    asm volatile("s_waitcnt vmcnt(0)" ::: "memory");
    if (lane == 0)
      __hip_atomic_store(myflag, (unsigned)(t + 1), __ATOMIC_RELAXED,
                         __HIP_MEMORY_SCOPE_AGENT);
    // non-critical stores after the signal (cross-dispatch consumers only)
    if (h1c){
      #pragma unroll
      for (int q = 0; q < 4; ++q)
        h1c[((size_t)(myrow0 + r4 + q) * TC + tl) * HH + c0 + fr] = hb[q];
    }
    if (tl == TC - 1){
      #pragma unroll
      for (int q = 0; q < 4; ++q)
        hstate[(size_t)(myrow0 + r4 + q) * HH + c0 + fr] = hn[q];
    }
    // NO barrier: Ws is read-only, no shared step state
  }
}

// --------- fused dispatch: 128 WGs role A (L0 chunk c) || 128 WGs role B (L1 chunk c-1)
__global__ __launch_bounds__(128, 1) void gru_fused(
    const u16* gxA, const u16* WhhA, const float* bhhA, u16* hbufA,
    unsigned* flA, u16* h1cA, float* hstA, int baseA,
    const u16* gxB, const u16* WhhB, const float* bhhB, u16* hbufB,
    unsigned* flB, float* hstB, int baseB)
{
  __shared__ u16 Ws[48 * 1032];      // ~97KB
  int blk = blockIdx.x;
  if (blk < 128){
    if (!gxA) return;
    gru_chunk(gxA, WhhA, bhhA, hbufA, flA, h1cA, hstA, baseA, blk, Ws);
  } else {
    if (!gxB) return;
    gru_chunk(gxB, WhhB, bhhB, hbufB, flB, nullptr, hstB, baseB, blk - 128, Ws);
  }
}

// ---------------------------------------------------- x_projected[:, -1, :] (f32)
__global__ __launch_bounds__(256) void xproj_kernel(const float* __restrict__ x,
    const float* __restrict__ wproj, const float* __restrict__ bproj, float* __restrict__ xp){
  __shared__ float xs[II];
  int b = blockIdx.x >> 2, n0 = (blockIdx.x & 3) << 8;
  const float* xrow = x + ((size_t)b * TT + (TT - 1)) * II;
  for (int i = threadIdx.x; i < II; i += 256) xs[i] = xrow[i];
  __syncthreads();
  int n = n0 + threadIdx.x;
  const float* wrow = wproj + (size_t)n * II;
  float s = 0.f;
  #pragma unroll 4
  for (int k = 0; k < II; k += 4){
    float4 w4 = *reinterpret_cast<const float4*>(&wrow[k]);
    s += xs[k]*w4.x + xs[k+1]*w4.y + xs[k+2]*w4.z + xs[k+3]*w4.w;
  }
  xp[(size_t)b * HH + n] = s + bproj[n];
}

// ------------------------------------- residual + BN(inference) + out GEMM (f32)
__global__ __launch_bounds__(256) void final_kernel(const float* __restrict__ xp,
    const float* __restrict__ hl, const float* __restrict__ gamma, const float* __restrict__ beta,
    const float* __restrict__ mean, const float* __restrict__ var,
    const float* __restrict__ wout, const float* __restrict__ bout, float* __restrict__ out){
  __shared__ float bn[2 * HH];
  int b0 = blockIdx.x * 2;
  for (int i = threadIdx.x; i < 2 * HH; i += 256){
    int bb = i >> 10, jj = i & (HH - 1);
    float res = xp[(size_t)(b0 + bb) * HH + jj] + hl[(size_t)(b0 + bb) * HH + jj];
    bn[i] = (res - mean[jj]) * rsqrtf(var[jj] + 1e-5f) * gamma[jj] + beta[jj];
  }
  __syncthreads();
  int bb = threadIdx.x >> 7, o = threadIdx.x & (OO - 1);
  const float* wrow = wout + (size_t)o * HH;
  const float* bnrow = bn + bb * HH;
  float s = 0.f;
  #pragma unroll 4
  for (int k = 0; k < HH; k += 4){
    float4 w4 = *reinterpret_cast<const float4*>(&wrow[k]);
    s += bnrow[k]*w4.x + bnrow[k+1]*w4.y + bnrow[k+2]*w4.z + bnrow[k+3]*w4.w;
  }
  out[(size_t)(b0 + bb) * OO + o] = s + bout[o];
}

extern "C" void kernel_launch(void* const* d_in, const int* in_sizes, int n_in,
                              void* d_out, int out_size, void* d_ws, size_t ws_size,
                              hipStream_t stream) {
  const float* x      = (const float*)d_in[0];
  const float* w_proj = (const float*)d_in[1];
  const float* b_proj = (const float*)d_in[2];
  const float* w_ih0  = (const float*)d_in[3];
  const float* w_hh0  = (const float*)d_in[4];
  const float* b_ih0  = (const float*)d_in[5];
  const float* b_hh0  = (const float*)d_in[6];
  const float* w_ih1  = (const float*)d_in[7];
  const float* w_hh1  = (const float*)d_in[8];
  const float* b_ih1  = (const float*)d_in[9];
  const float* b_hh1  = (const float*)d_in[10];
  const float* gamma  = (const float*)d_in[11];
  const float* beta   = (const float*)d_in[12];
  const float* mean   = (const float*)d_in[13];
  const float* var    = (const float*)d_in[14];
  const float* w_out  = (const float*)d_in[15];
  const float* b_out  = (const float*)d_in[16];
  float* out = (float*)d_out;

  char* ws = (char*)d_ws;
  size_t off = 0;
  unsigned* flA  = (unsigned*)(ws + off); off += (size_t)2*64*2*16*4;      // 16 KB
  unsigned* flB  = (unsigned*)(ws + off); off += (size_t)2*64*2*16*4;      // 16 KB
  float* hst0  = (float*)(ws + off); off += (size_t)BB*HH*4;               // 256 KB
  float* hst1  = (float*)(ws + off); off += (size_t)BB*HH*4;
  size_t zeroA = off;                                                      // flags+hstates
  u16* hbuf0   = (u16*)(ws + off);   off += (size_t)NSLOT*BB*HH*2;         // 8.5 MB
  u16* hbuf1   = (u16*)(ws + off);   off += (size_t)NSLOT*BB*HH*2;
  float* xproj = (float*)(ws + off); off += (size_t)BB*HH*4;
  u16* xck     = (u16*)(ws + off);   off += (size_t)BB*TC*II*2;            // 4.2 MB
  u16* h1c     = (u16*)(ws + off);   off += (size_t)BB*TC*HH*2;            // 8.4 MB
  u16* wih0b   = (u16*)(ws + off);   off += (size_t)3*HH*II*2;             // 3.1 MB
  u16* whh0b   = (u16*)(ws + off);   off += (size_t)3*HH*HH*2;             // 6.3 MB
  u16* wih1b   = (u16*)(ws + off);   off += (size_t)3*HH*HH*2;
  u16* whh1b   = (u16*)(ws + off);   off += (size_t)3*HH*HH*2;
  u16* gxc0    = (u16*)(ws + off);   off += (size_t)BB*TC*3*HH*2;          // 25.2 MB
  u16* gxc1    = (u16*)(ws + off);   off += (size_t)BB*TC*3*HH*2;
  // total ~104 MB

  hipMemsetAsync(d_ws, 0, zeroA, stream);                    // flags + hstates

  cvt_kernel<<<512, 256, 0, stream>>>(w_ih0, wih0b, (3*HH*II) / 4);
  cvt_kernel<<<512, 256, 0, stream>>>(w_hh0, whh0b, (3*HH*HH) / 4);
  cvt_kernel<<<512, 256, 0, stream>>>(w_ih1, wih1b, (3*HH*HH) / 4);
  cvt_kernel<<<512, 256, 0, stream>>>(w_hh1, whh1b, (3*HH*HH) / 4);

  xproj_kernel<<<256, 256, 0, stream>>>(x, w_proj, b_proj, xproj);

  dim3 ggrid(BB * TC / 128, GN / 128);           // (32, 24)

  // prologue: L0 chunk 0 alone
  cvtx_chunk<<<1024, 256, 0, stream>>>(x, xck, 0);
  gemm_bias<II><<<ggrid, 256, 0, stream>>>(xck, wih0b, b_ih0, gxc0);
  gru_fused<<<256, 128, 0, stream>>>(gxc0, whh0b, b_hh0, hbuf0, flA, h1c, hst0, 0,
                                     nullptr, whh1b, b_hh1, hbuf1, flB, hst1, 0);
  // steady state: L0(k) || L1(k-1)
  for (int k = 1; k < NCH; ++k){
    gemm_bias<HH><<<ggrid, 256, 0, stream>>>(h1c, wih1b, b_ih1, gxc1);   // gx1(k-1)
    cvtx_chunk<<<1024, 256, 0, stream>>>(x, xck, k * TC);
    gemm_bias<II><<<ggrid, 256, 0, stream>>>(xck, wih0b, b_ih0, gxc0);   // gx0(k)
    gru_fused<<<256, 128, 0, stream>>>(gxc0, whh0b, b_hh0, hbuf0, flA, h1c, hst0, k*TC,
                                       gxc1, whh1b, b_hh1, hbuf1, flB, hst1, (k-1)*TC);
  }
  // epilogue: L1 chunk 7 alone
  gemm_bias<HH><<<ggrid, 256, 0, stream>>>(h1c, wih1b, b_ih1, gxc1);
  gru_fused<<<256, 128, 0, stream>>>(nullptr, whh0b, b_hh0, hbuf0, flA, h1c, hst0, 0,
                                     gxc1, whh1b, b_hh1, hbuf1, flB, hst1, (NCH-1)*TC);

  final_kernel<<<BB / 2, 256, 0, stream>>>(xproj, hst1, gamma, beta, mean, var, w_out, b_out, out);
}

// Round 10
// 4364.729 us; speedup vs baseline: 1.2103x; 1.2103x over previous
//
#include <hip/hip_runtime.h>
#include <math.h>

// Problem constants
#define BB 64
#define TT 512
#define II 512
#define HH 1024
#define OO 128
#define GN (3*HH)       // 3072
#define TC 64           // time chunk
#define NCH (TT/TC)     // 8 chunks
#define NSLOT 66        // rolling h slots: slot 0 = initial zeros, 1..65 rotate
#define NBAR 129        // barriers per gru_fused: 1 (W stage) + 2*TC

using u16 = unsigned short;
typedef __attribute__((ext_vector_type(8))) short bf16x8;
typedef __attribute__((ext_vector_type(4))) float f32x4;
typedef __attribute__((ext_vector_type(4))) unsigned short u16x4;

__device__ __forceinline__ u16 f2bf(float f){
  unsigned u = __builtin_bit_cast(unsigned, f);
  u += 0x7fffu + ((u >> 16) & 1u);          // RNE
  return (u16)(u >> 16);
}
__device__ __forceinline__ float bf2f(u16 h){
  unsigned u = ((unsigned)h) << 16;
  return __builtin_bit_cast(float, u);
}

// ---------------------------------------------------------------- f32 -> bf16
__global__ __launch_bounds__(256) void cvt_kernel(const float* __restrict__ s,
                                                  u16* __restrict__ d, int n4){
  int stride = gridDim.x * 256;
  for (int i = blockIdx.x * 256 + threadIdx.x; i < n4; i += stride){
    float4 v = reinterpret_cast<const float4*>(s)[i];
    u16x4 o; o.x = f2bf(v.x); o.y = f2bf(v.y); o.z = f2bf(v.z); o.w = f2bf(v.w);
    reinterpret_cast<u16x4*>(d)[i] = o;
  }
}

// --------------------------------------------- x chunk gather+convert to bf16
__global__ __launch_bounds__(256) void cvtx_chunk(const float* __restrict__ x,
                                                  u16* __restrict__ d, int t0){
  const int per_b = TC * II / 4;
  int stride = gridDim.x * 256;
  for (int i = blockIdx.x * 256 + threadIdx.x; i < BB * per_b; i += stride){
    int b = i / per_b, r = i - b * per_b;
    float4 v = reinterpret_cast<const float4*>(x)[(size_t)(b * TT + t0) * (II/4) + r];
    u16x4 o; o.x = f2bf(v.x); o.y = f2bf(v.y); o.z = f2bf(v.z); o.w = f2bf(v.w);
    reinterpret_cast<u16x4*>(d)[(size_t)b * per_b + r] = o;
  }
}

// ------------------------------------------------- bf16 GEMM: C = A@Bw^T + bias
// m97 structure: 128x128 tile, BK=32, 4 waves, global_load_lds width 16.
template<int K>
__global__ __launch_bounds__(256) void gemm_bias(const u16* __restrict__ A,
    const u16* __restrict__ Bw, const float* __restrict__ bias, u16* __restrict__ C){
  __shared__ u16 As[128*32];
  __shared__ u16 Bs[128*32];
  int tid = threadIdx.x;
  int lane = tid & 63, wave = tid >> 6;
  int m0 = blockIdx.x * 128, n0 = blockIdx.y * 128;
  int wr = (wave >> 1) * 64, wc = (wave & 1) * 64;
  int fr = lane & 15, fo = (lane >> 4) * 8;
  f32x4 acc[4][4] = {};
  for (int k0 = 0; k0 < K; k0 += 32){
    __syncthreads();
    #pragma unroll
    for (int c = 0; c < 2; ++c){
      int chunk = wave * 2 + c;
      int s = chunk * 64 + lane;
      int row = s >> 2, o = s & 3;
      const u16* ga = A  + (size_t)(m0 + row) * K + k0 + o * 8;
      const u16* gb = Bw + (size_t)(n0 + row) * K + k0 + o * 8;
      __builtin_amdgcn_global_load_lds(
          (const __attribute__((address_space(1))) unsigned int*)ga,
          (__attribute__((address_space(3))) unsigned int*)(As + chunk * 512), 16, 0, 0);
      __builtin_amdgcn_global_load_lds(
          (const __attribute__((address_space(1))) unsigned int*)gb,
          (__attribute__((address_space(3))) unsigned int*)(Bs + chunk * 512), 16, 0, 0);
    }
    __syncthreads();
    bf16x8 af[4], bf[4];
    #pragma unroll
    for (int m = 0; m < 4; ++m)
      af[m] = *reinterpret_cast<const bf16x8*>(&As[(wr + m*16 + fr) * 32 + fo]);
    #pragma unroll
    for (int n = 0; n < 4; ++n)
      bf[n] = *reinterpret_cast<const bf16x8*>(&Bs[(wc + n*16 + fr) * 32 + fo]);
    #pragma unroll
    for (int m = 0; m < 4; ++m)
      #pragma unroll
      for (int n = 0; n < 4; ++n)
        acc[m][n] = __builtin_amdgcn_mfma_f32_16x16x32_bf16(af[m], bf[n], acc[m][n], 0, 0, 0);
  }
  int r4 = (lane >> 4) * 4;
  #pragma unroll
  for (int n = 0; n < 4; ++n){
    int col = n0 + wc + n*16 + fr;
    float bv = bias[col];
    #pragma unroll
    for (int m = 0; m < 4; ++m){
      #pragma unroll
      for (int q = 0; q < 4; ++q){
        int row = m0 + wr + m*16 + r4 + q;
        C[(size_t)row * GN + col] = f2bf(acc[m][n][q] + bv);
      }
    }
  }
}

// --------------------------------------------------- GRU chunk body (R7, proven 295us)
// Per role: 128 WGs (threads 0-255) = 2 batch-groups(32 rows) x 64 col-slices(16).
// W slice in LDS; rolling 66-slot hbuf; producer relaxed agent atomic 2B stores +
// WG __syncthreads (vmcnt drain) + per-WG flag; consumer polls 64 flags (1/lane),
// then PLAIN CACHED 16B h loads (first-touch per dispatch). Exactly NBAR=129
// __syncthreads executed by every wave.
__device__ __forceinline__ void gru_chunk(
    const u16* __restrict__ gx, const u16* __restrict__ Whh, const float* __restrict__ bhh,
    u16* hbuf, unsigned* flags, u16* h1c, float* hstate, int base,
    int bl, u16* Ws, float* part, float* bsh)
{
  int tid = threadIdx.x, lane = tid & 63, w = tid >> 6;
  int g = bl >> 6, wg = bl & 63;
  int c0 = wg * 16, rb0 = g * 32;
  for (int ch = tid; ch < 48 * 128; ch += 256){
    int r = ch >> 7, o = ch & 127;
    const u16* src = Whh + (size_t)((r >> 4) * HH + c0 + (r & 15)) * HH + o * 8;
    *reinterpret_cast<int4*>(&Ws[r * 1032 + o * 8]) = *reinterpret_cast<const int4*>(src);
  }
  if (tid < 48) bsh[tid] = bhh[(tid >> 4) * HH + c0 + (tid & 15)];
  __syncthreads();                                           // barrier #1
  int b2 = tid >> 4, j = tid & 15;
  int fr = lane & 15, klo = (lane >> 4) * 8, kw = w * 256;
  const u16* gxp0 = gx + (size_t)(rb0 + b2) * TC * GN + c0 + j;
  const u16* gxp1 = gx + (size_t)(rb0 + 16 + b2) * TC * GN + c0 + j;
  unsigned* fgrp = flags + g * 1024;           // 64 WGs x 16 u32 (64B padded)
  float ho0 = hstate[(size_t)(rb0 + b2) * HH + c0 + j];
  float ho1 = hstate[(size_t)(rb0 + 16 + b2) * HH + c0 + j];
  int lnD = (b2 >> 2) * 16 + j, regD = b2 & 3; // D map: col=lane&15,row=(lane>>4)*4+reg
  float br = bhh[c0 + j];
  for (int tl = 0; tl < TC; ++tl){
    int t = base + tl;
    // gx loads are h-independent — issue before the wait, overlap the poll
    float gxr0 = bf2f(gxp0[(size_t)tl * GN]);
    float gxz0 = bf2f(gxp0[(size_t)tl * GN + HH]);
    float gxn0 = bf2f(gxp0[(size_t)tl * GN + 2 * HH]);
    float gxr1 = bf2f(gxp1[(size_t)tl * GN]);
    float gxz1 = bf2f(gxp1[(size_t)tl * GN + HH]);
    float gxn1 = bf2f(gxp1[(size_t)tl * GN + 2 * HH]);
    if (tl){
      for (;;){
        unsigned v = __hip_atomic_load(fgrp + lane * 16, __ATOMIC_RELAXED,
                                       __HIP_MEMORY_SCOPE_AGENT);
        if (__all((int)(v >= (unsigned)tl))) break;
        __builtin_amdgcn_s_sleep(1);
      }
    }
    asm volatile("" ::: "memory");   // keep h loads below the poll
    // h loads: PLAIN CACHED 16B loads from the read slot (first-touch)
    const u16* rslot = hbuf + (size_t)(((t - 1) % 65) + 1) * (BB * HH);
    const u16* hr0 = rslot + (size_t)(rb0 + fr) * HH + kw + klo;
    const u16* hr1 = hr0 + (size_t)16 * HH;
    bf16x8 af0[8], af1[8];
    #pragma unroll
    for (int ks = 0; ks < 8; ++ks){
      af0[ks] = *reinterpret_cast<const bf16x8*>(hr0 + ks * 32);
      af1[ks] = *reinterpret_cast<const bf16x8*>(hr1 + ks * 32);
    }
    f32x4 acc[2][3] = {};
    #pragma unroll
    for (int ks = 0; ks < 8; ++ks){
      int kk = kw + ks * 32 + klo;
      bf16x8 w0 = *reinterpret_cast<const bf16x8*>(&Ws[(      fr) * 1032 + kk]);
      bf16x8 w1 = *reinterpret_cast<const bf16x8*>(&Ws[(16 + fr) * 1032 + kk]);
      bf16x8 w2 = *reinterpret_cast<const bf16x8*>(&Ws[(32 + fr) * 1032 + kk]);
      acc[0][0] = __builtin_amdgcn_mfma_f32_16x16x32_bf16(af0[ks], w0, acc[0][0], 0, 0, 0);
      acc[0][1] = __builtin_amdgcn_mfma_f32_16x16x32_bf16(af0[ks], w1, acc[0][1], 0, 0, 0);
      acc[0][2] = __builtin_amdgcn_mfma_f32_16x16x32_bf16(af0[ks], w2, acc[0][2], 0, 0, 0);
      acc[1][0] = __builtin_amdgcn_mfma_f32_16x16x32_bf16(af1[ks], w0, acc[1][0], 0, 0, 0);
      acc[1][1] = __builtin_amdgcn_mfma_f32_16x16x32_bf16(af1[ks], w1, acc[1][1], 0, 0, 0);
      acc[1][2] = __builtin_amdgcn_mfma_f32_16x16x32_bf16(af1[ks], w2, acc[1][2], 0, 0, 0);
    }
    #pragma unroll
    for (int at = 0; at < 2; ++at)
      #pragma unroll
      for (int gt = 0; gt < 3; ++gt)
        *reinterpret_cast<f32x4*>(&part[((w*6 + at*3 + gt)*64 + lane)*4]) = acc[at][gt];
    __syncthreads();                                         // barrier #2k
    float gh[2][3];
    #pragma unroll
    for (int at = 0; at < 2; ++at)
      #pragma unroll
      for (int gt = 0; gt < 3; ++gt){
        float s = 0.f;
        #pragma unroll
        for (int ww = 0; ww < 4; ++ww)
          s += part[((ww*6 + at*3 + gt)*64 + lnD)*4 + regD];
        gh[at][gt] = s;
      }
    float bz = bsh[16 + j], bn2 = bsh[32 + j];
    float r0 = __builtin_amdgcn_rcpf(1.f + __expf(-(gxr0 + gh[0][0] + br)));
    float z0 = __builtin_amdgcn_rcpf(1.f + __expf(-(gxz0 + gh[0][1] + bz)));
    float nx0 = gxn0 + r0 * (gh[0][2] + bn2);
    float n0 = 1.f - 2.f * __builtin_amdgcn_rcpf(__expf(2.f * nx0) + 1.f);
    float hn0 = (1.f - z0) * n0 + z0 * ho0;
    float r1 = __builtin_amdgcn_rcpf(1.f + __expf(-(gxr1 + gh[1][0] + br)));
    float z1 = __builtin_amdgcn_rcpf(1.f + __expf(-(gxz1 + gh[1][1] + bz)));
    float nx1 = gxn1 + r1 * (gh[1][2] + bn2);
    float n1 = 1.f - 2.f * __builtin_amdgcn_rcpf(__expf(2.f * nx1) + 1.f);
    float hn1 = (1.f - z1) * n1 + z1 * ho1;
    ho0 = hn0; ho1 = hn1;                        // f32 self-path
    u16 hb0 = f2bf(hn0), hb1 = f2bf(hn1);
    // h stores: device-scope write-through to LLC at the write slot
    u16* wslot = hbuf + (size_t)((t % 65) + 1) * (BB * HH);
    size_t d0 = (size_t)(rb0 + b2) * HH + c0 + j;
    __hip_atomic_store(wslot + d0,                hb0, __ATOMIC_RELAXED, __HIP_MEMORY_SCOPE_AGENT);
    __hip_atomic_store(wslot + d0 + (size_t)16*HH, hb1, __ATOMIC_RELAXED, __HIP_MEMORY_SCOPE_AGENT);
    if (h1c){
      h1c[((size_t)(rb0 + b2) * TC + tl) * HH + c0 + j] = hb0;
      h1c[((size_t)(rb0 + 16 + b2) * TC + tl) * HH + c0 + j] = hb1;
    }
    if (tl == TC - 1){
      hstate[(size_t)(rb0 + b2) * HH + c0 + j] = hn0;
      hstate[(size_t)(rb0 + 16 + b2) * HH + c0 + j] = hn1;
    }
    __syncthreads();   // barrier #2k+1: vmcnt(0) drain of all WG h-stores
    if (tid == 0)
      __hip_atomic_store(fgrp + wg * 16, (unsigned)(tl + 1), __ATOMIC_RELAXED,
                         __HIP_MEMORY_SCOPE_AGENT);
  }
}

// ----------------- role C: gx0 GEMM for NEXT chunk (x-dependent only, uncoupled)
// 4 waves/WG (threads 256-511). 48 16x16 K=512 output tiles per wave, one per
// long interval; A = x f32 inline-converted, B = wih0b from L2. Exactly NBAR
// __syncthreads (co-routine with gru_chunk's barrier schedule).
__device__ __forceinline__ void role_c_gemm(
    const float* __restrict__ x, const u16* __restrict__ Wih,
    const float* __restrict__ bih, u16* __restrict__ dst, int t0c, int gw)
{
  int lane = threadIdx.x & 63;
  int fr = lane & 15, klo = (lane >> 4) * 8, r4 = (lane >> 4) * 4;
  bool hasC = (t0c < TT) && (dst != nullptr);
  int done = 0;
  for (int it = 0; it < NBAR; ++it){
    if (hasC && done < 48 && (it == 0 || (it & 1))){
      int tile = gw * 48 + done; ++done;
      int tm = tile / 192, tn = tile - tm * 192;
      int m0 = tm * 16, n0 = tn * 16;
      int mrow = m0 + fr;
      int b = mrow >> 6, tl = mrow & 63;
      const float* xr = x + ((size_t)b * TT + t0c + tl) * II + klo;
      const u16* br = Wih + (size_t)(n0 + fr) * II + klo;
      f32x4 acc = {};
      #pragma unroll
      for (int ks = 0; ks < 16; ++ks){
        float4 a0 = *reinterpret_cast<const float4*>(xr + ks * 32);
        float4 a1 = *reinterpret_cast<const float4*>(xr + ks * 32 + 4);
        u16x4 p0, p1;
        p0.x = f2bf(a0.x); p0.y = f2bf(a0.y); p0.z = f2bf(a0.z); p0.w = f2bf(a0.w);
        p1.x = f2bf(a1.x); p1.y = f2bf(a1.y); p1.z = f2bf(a1.z); p1.w = f2bf(a1.w);
        struct { u16x4 lo, hi; } packed{p0, p1};
        bf16x8 af = __builtin_bit_cast(bf16x8, packed);
        bf16x8 bf = *reinterpret_cast<const bf16x8*>(br + ks * 32);
        acc = __builtin_amdgcn_mfma_f32_16x16x32_bf16(af, bf, acc, 0, 0, 0);
      }
      float bv = bih[n0 + fr];
      #pragma unroll
      for (int q = 0; q < 4; ++q)
        dst[(size_t)(m0 + r4 + q) * GN + (n0 + fr)] = f2bf(acc[q] + bv);
    }
    __syncthreads();
  }
}

// ------- fused dispatch: threads 0-255 = recurrence (blk<128: L0(c); else L1(c-1));
//         threads 256-511 = role C (gx0 GEMM for chunk c+1). 129-barrier co-routine.
__global__ __launch_bounds__(512, 1) void gru_fused(
    const u16* gxA, const u16* WhhA, const float* bhhA, u16* hbufA,
    unsigned* flA, u16* h1cA, float* hstA, int baseA,
    const u16* gxB, const u16* WhhB, const float* bhhB, u16* hbufB,
    unsigned* flB, float* hstB, int baseB,
    const float* x, const u16* wihC, const float* bihC, u16* gxoutC, int t0c)
{
  __shared__ u16 Ws[48 * 1032];      // 99KB
  __shared__ float part[4*6*64*4];   // 24KB
  __shared__ float bsh[48];
  int tid = threadIdx.x;
  int blk = blockIdx.x;
  if (tid < 256){
    const u16* gx = (blk < 128) ? gxA : gxB;
    if (gx){
      if (blk < 128)
        gru_chunk(gxA, WhhA, bhhA, hbufA, flA, h1cA, hstA, baseA, blk, Ws, part, bsh);
      else
        gru_chunk(gxB, WhhB, bhhB, hbufB, flB, nullptr, hstB, baseB, blk - 128, Ws, part, bsh);
    } else {
      for (int i = 0; i < NBAR; ++i) __syncthreads();        // barrier tail
    }
  } else {
    int gw = blk * 4 + ((tid >> 6) - 4);                     // 0..1023
    role_c_gemm(x, wihC, bihC, gxoutC, t0c, gw);
  }
}

// ---------------------------------------------------- x_projected[:, -1, :] (f32)
__global__ __launch_bounds__(256) void xproj_kernel(const float* __restrict__ x,
    const float* __restrict__ wproj, const float* __restrict__ bproj, float* __restrict__ xp){
  __shared__ float xs[II];
  int b = blockIdx.x >> 2, n0 = (blockIdx.x & 3) << 8;
  const float* xrow = x + ((size_t)b * TT + (TT - 1)) * II;
  for (int i = threadIdx.x; i < II; i += 256) xs[i] = xrow[i];
  __syncthreads();
  int n = n0 + threadIdx.x;
  const float* wrow = wproj + (size_t)n * II;
  float s = 0.f;
  #pragma unroll 4
  for (int k = 0; k < II; k += 4){
    float4 w4 = *reinterpret_cast<const float4*>(&wrow[k]);
    s += xs[k]*w4.x + xs[k+1]*w4.y + xs[k+2]*w4.z + xs[k+3]*w4.w;
  }
  xp[(size_t)b * HH + n] = s + bproj[n];
}

// ------------------------------------- residual + BN(inference) + out GEMM (f32)
__global__ __launch_bounds__(256) void final_kernel(const float* __restrict__ xp,
    const float* __restrict__ hl, const float* __restrict__ gamma, const float* __restrict__ beta,
    const float* __restrict__ mean, const float* __restrict__ var,
    const float* __restrict__ wout, const float* __restrict__ bout, float* __restrict__ out){
  __shared__ float bn[2 * HH];
  int b0 = blockIdx.x * 2;
  for (int i = threadIdx.x; i < 2 * HH; i += 256){
    int bb = i >> 10, jj = i & (HH - 1);
    float res = xp[(size_t)(b0 + bb) * HH + jj] + hl[(size_t)(b0 + bb) * HH + jj];
    bn[i] = (res - mean[jj]) * rsqrtf(var[jj] + 1e-5f) * gamma[jj] + beta[jj];
  }
  __syncthreads();
  int bb = threadIdx.x >> 7, o = threadIdx.x & (OO - 1);
  const float* wrow = wout + (size_t)o * HH;
  const float* bnrow = bn + bb * HH;
  float s = 0.f;
  #pragma unroll 4
  for (int k = 0; k < HH; k += 4){
    float4 w4 = *reinterpret_cast<const float4*>(&wrow[k]);
    s += bnrow[k]*w4.x + bnrow[k+1]*w4.y + bnrow[k+2]*w4.z + bnrow[k+3]*w4.w;
  }
  out[(size_t)(b0 + bb) * OO + o] = s + bout[o];
}

extern "C" void kernel_launch(void* const* d_in, const int* in_sizes, int n_in,
                              void* d_out, int out_size, void* d_ws, size_t ws_size,
                              hipStream_t stream) {
  const float* x      = (const float*)d_in[0];
  const float* w_proj = (const float*)d_in[1];
  const float* b_proj = (const float*)d_in[2];
  const float* w_ih0  = (const float*)d_in[3];
  const float* w_hh0  = (const float*)d_in[4];
  const float* b_ih0  = (const float*)d_in[5];
  const float* b_hh0  = (const float*)d_in[6];
  const float* w_ih1  = (const float*)d_in[7];
  const float* w_hh1  = (const float*)d_in[8];
  const float* b_ih1  = (const float*)d_in[9];
  const float* b_hh1  = (const float*)d_in[10];
  const float* gamma  = (const float*)d_in[11];
  const float* beta   = (const float*)d_in[12];
  const float* mean   = (const float*)d_in[13];
  const float* var    = (const float*)d_in[14];
  const float* w_out  = (const float*)d_in[15];
  const float* b_out  = (const float*)d_in[16];
  float* out = (float*)d_out;

  char* ws = (char*)d_ws;
  size_t off = 0;
  unsigned* flags = (unsigned*)(ws + off); off += (size_t)18 * 2048 * 4;   // 144 KB
  float* hst0  = (float*)(ws + off); off += (size_t)BB*HH*4;               // 256 KB
  float* hst1  = (float*)(ws + off); off += (size_t)BB*HH*4;
  size_t zeroA = off;                                                      // flags+hstates
  u16* hbuf0   = (u16*)(ws + off);   off += (size_t)NSLOT*BB*HH*2;         // 8.65 MB
  u16* hbuf1   = (u16*)(ws + off);   off += (size_t)NSLOT*BB*HH*2;
  float* xproj = (float*)(ws + off); off += (size_t)BB*HH*4;
  u16* h1c     = (u16*)(ws + off);   off += (size_t)BB*TC*HH*2;            // 8.4 MB
  u16* wih0b   = (u16*)(ws + off);   off += (size_t)3*HH*II*2;             // 3.1 MB
  u16* whh0b   = (u16*)(ws + off);   off += (size_t)3*HH*HH*2;             // 6.3 MB
  u16* wih1b   = (u16*)(ws + off);   off += (size_t)3*HH*HH*2;
  u16* whh1b   = (u16*)(ws + off);   off += (size_t)3*HH*HH*2;
  u16* gxc1    = (u16*)(ws + off);   off += (size_t)BB*TC*3*HH*2;          // 25.2 MB
  u16* gxc0a   = (u16*)(ws + off);   off += (size_t)BB*TC*3*HH*2;          // 25.2 MB
  u16* gxc0b   = (u16*)(ws + off);   off += (size_t)BB*TC*3*HH*2;          // 25.2 MB
  u16* xck     = gxc0b;              // prologue-only staging aliases gxc0b
  // total ~125 MB

  hipMemsetAsync(d_ws, 0, zeroA, stream);                    // flags + hstates
  hipMemsetAsync(hbuf0, 0, (size_t)BB*HH*2, stream);         // slot 0 = h(-1) = 0
  hipMemsetAsync(hbuf1, 0, (size_t)BB*HH*2, stream);

  cvt_kernel<<<512, 256, 0, stream>>>(w_ih0, wih0b, (3*HH*II) / 4);
  cvt_kernel<<<512, 256, 0, stream>>>(w_hh0, whh0b, (3*HH*HH) / 4);
  cvt_kernel<<<512, 256, 0, stream>>>(w_ih1, wih1b, (3*HH*HH) / 4);
  cvt_kernel<<<512, 256, 0, stream>>>(w_hh1, whh1b, (3*HH*HH) / 4);

  xproj_kernel<<<256, 256, 0, stream>>>(x, w_proj, b_proj, xproj);

  dim3 ggrid(BB * TC / 128, GN / 128);           // (32, 24)
  auto fl = [&](int k, int role){ return flags + (size_t)(k*2 + role) * 2048; };
  u16* gxc0[2] = { gxc0a, gxc0b };

  // prologue: gx0 chunk 0 serial (xck aliases gxc0b, fully read before role C writes it)
  cvtx_chunk<<<1024, 256, 0, stream>>>(x, xck, 0);
  gemm_bias<II><<<ggrid, 256, 0, stream>>>(xck, wih0b, b_ih0, gxc0[0]);
  // dispatch 0: role A = L0 chunk 0; role C computes gx0 chunk 1 -> gxc0[1]
  gru_fused<<<256, 512, 0, stream>>>(gxc0[0], whh0b, b_hh0, hbuf0, fl(0,0), h1c, hst0, 0,
                                     nullptr, whh1b, b_hh1, hbuf1, fl(0,1), hst1, 0,
                                     x, wih0b, b_ih0, gxc0[1], TC);
  // steady state: L0(k) || L1(k-1) || roleC gx0(k+1)
  for (int k = 1; k < NCH; ++k){
    gemm_bias<HH><<<ggrid, 256, 0, stream>>>(h1c, wih1b, b_ih1, gxc1);   // gx1(k-1)
    gru_fused<<<256, 512, 0, stream>>>(gxc0[k & 1], whh0b, b_hh0, hbuf0, fl(k,0), h1c, hst0, k*TC,
                                       gxc1, whh1b, b_hh1, hbuf1, fl(k,1), hst1, (k-1)*TC,
                                       x, wih0b, b_ih0, gxc0[(k + 1) & 1], (k + 1) * TC);
  }
  // epilogue: L1 chunk 7 alone (role C idle: t0c >= TT)
  gemm_bias<HH><<<ggrid, 256, 0, stream>>>(h1c, wih1b, b_ih1, gxc1);
  gru_fused<<<256, 512, 0, stream>>>(nullptr, whh0b, b_hh0, hbuf0, fl(8,0), h1c, hst0, 0,
                                     gxc1, whh1b, b_hh1, hbuf1, fl(8,1), hst1, (NCH-1)*TC,
                                     x, wih0b, b_ih0, nullptr, TT);

  final_kernel<<<BB / 2, 256, 0, stream>>>(xproj, hst1, gamma, beta, mean, var, w_out, b_out, out);
}

// Round 11
// 3317.836 us; speedup vs baseline: 1.5922x; 1.3155x over previous
//
#include <hip/hip_runtime.h>
#include <math.h>

// Problem constants
#define BB 64
#define TT 512
#define II 512
#define HH 1024
#define OO 128
#define GN (3*HH)       // 3072
#define TC 64           // time chunk
#define NCH (TT/TC)     // 8 chunks
#define NSLOT 66        // rolling h slots: slot 0 = initial zeros, 1..65 rotate

using u16 = unsigned short;
typedef __attribute__((ext_vector_type(8))) short bf16x8;
typedef __attribute__((ext_vector_type(4))) float f32x4;
typedef __attribute__((ext_vector_type(4))) unsigned short u16x4;

__device__ __forceinline__ u16 f2bf(float f){
  unsigned u = __builtin_bit_cast(unsigned, f);
  u += 0x7fffu + ((u >> 16) & 1u);          // RNE
  return (u16)(u >> 16);
}
__device__ __forceinline__ float bf2f(u16 h){
  unsigned u = ((unsigned)h) << 16;
  return __builtin_bit_cast(float, u);
}

// ---------------------------------------------------------------- f32 -> bf16
__global__ __launch_bounds__(256) void cvt_kernel(const float* __restrict__ s,
                                                  u16* __restrict__ d, int n4){
  int stride = gridDim.x * 256;
  for (int i = blockIdx.x * 256 + threadIdx.x; i < n4; i += stride){
    float4 v = reinterpret_cast<const float4*>(s)[i];
    u16x4 o; o.x = f2bf(v.x); o.y = f2bf(v.y); o.z = f2bf(v.z); o.w = f2bf(v.w);
    reinterpret_cast<u16x4*>(d)[i] = o;
  }
}

// ------------------------------------------------- bf16 GEMM body (m97 structure)
// C[m, n] = A@Bw^T + bias over a 128x128 tile. BK=32, 4 waves, global_load_lds
// width 16. XMAP=true: A rows map through full-sequence layout [B,TT,K]:
// chunk-row r -> global row (r>>6)*TT + (r&63)  (TC=64 rows per batch).
template<int K, bool XMAP>
__device__ __forceinline__ void gemm_body(const u16* __restrict__ A,
    const u16* __restrict__ Bw, const float* __restrict__ bias, u16* __restrict__ C,
    int m0, int n0, u16* As, u16* Bs)
{
  int tid = threadIdx.x;
  int lane = tid & 63, wave = tid >> 6;
  int wr = (wave >> 1) * 64, wc = (wave & 1) * 64;
  int fr = lane & 15, fo = (lane >> 4) * 8;
  f32x4 acc[4][4] = {};
  for (int k0 = 0; k0 < K; k0 += 32){
    __syncthreads();
    #pragma unroll
    for (int c = 0; c < 2; ++c){
      int chunk = wave * 2 + c;
      int s = chunk * 64 + lane;
      int row = s >> 2, o = s & 3;
      int ar = m0 + row;
      size_t aoff = XMAP ? ((size_t)(ar >> 6) * TT + (ar & 63)) * K
                         : (size_t)ar * K;
      const u16* ga = A  + aoff + k0 + o * 8;
      const u16* gb = Bw + (size_t)(n0 + row) * K + k0 + o * 8;
      __builtin_amdgcn_global_load_lds(
          (const __attribute__((address_space(1))) unsigned int*)ga,
          (__attribute__((address_space(3))) unsigned int*)(As + chunk * 512), 16, 0, 0);
      __builtin_amdgcn_global_load_lds(
          (const __attribute__((address_space(1))) unsigned int*)gb,
          (__attribute__((address_space(3))) unsigned int*)(Bs + chunk * 512), 16, 0, 0);
    }
    __syncthreads();
    bf16x8 af[4], bf[4];
    #pragma unroll
    for (int m = 0; m < 4; ++m)
      af[m] = *reinterpret_cast<const bf16x8*>(&As[(wr + m*16 + fr) * 32 + fo]);
    #pragma unroll
    for (int n = 0; n < 4; ++n)
      bf[n] = *reinterpret_cast<const bf16x8*>(&Bs[(wc + n*16 + fr) * 32 + fo]);
    #pragma unroll
    for (int m = 0; m < 4; ++m)
      #pragma unroll
      for (int n = 0; n < 4; ++n)
        acc[m][n] = __builtin_amdgcn_mfma_f32_16x16x32_bf16(af[m], bf[n], acc[m][n], 0, 0, 0);
  }
  int r4 = (lane >> 4) * 4;
  #pragma unroll
  for (int n = 0; n < 4; ++n){
    int col = n0 + wc + n*16 + fr;
    float bv = bias[col];
    #pragma unroll
    for (int m = 0; m < 4; ++m){
      #pragma unroll
      for (int q = 0; q < 4; ++q){
        int row = m0 + wr + m*16 + r4 + q;
        C[(size_t)row * GN + col] = f2bf(acc[m][n][q] + bv);
      }
    }
  }
}

template<int K, bool XMAP>
__global__ __launch_bounds__(256) void gemm_bias(const u16* __restrict__ A,
    const u16* __restrict__ Bw, const float* __restrict__ bias, u16* __restrict__ C){
  __shared__ u16 As[128*32];
  __shared__ u16 Bs[128*32];
  gemm_body<K, XMAP>(A, Bw, bias, C, blockIdx.x * 128, blockIdx.y * 128, As, Bs);
}

// Combined dispatch: job0 (y<24) = gx1 GEMM (A=h1c, K=HH); job1 (y>=24) = gx0
// GEMM (A=xb chunk base, K=II, XMAP). Independent jobs, one launch.
__global__ __launch_bounds__(256) void gemm2(
    const u16* __restrict__ A0, const u16* __restrict__ B0,
    const float* __restrict__ b0, u16* __restrict__ C0,
    const u16* __restrict__ A1, const u16* __restrict__ B1,
    const float* __restrict__ b1, u16* __restrict__ C1)
{
  __shared__ u16 As[128*32];
  __shared__ u16 Bs[128*32];
  if (blockIdx.y < GN/128)
    gemm_body<HH, false>(A0, B0, b0, C0, blockIdx.x * 128, blockIdx.y * 128, As, Bs);
  else
    gemm_body<II, true >(A1, B1, b1, C1, blockIdx.x * 128,
                         (blockIdx.y - GN/128) * 128, As, Bs);
}

// --------------------------------------------------- GRU chunk body (R7, proven)
// Per role: 128 WGs = 2 batch-groups(32 rows) x 64 col-slices(16 cols).
// W slice in LDS; rolling 66-slot hbuf; producer relaxed agent atomic 2B stores +
// WG __syncthreads (vmcnt drain) + per-WG flag; consumer polls 64 flags (1/lane),
// then PLAIN CACHED 16B h loads (first-touch per dispatch). [R7: 295us/dispatch;
// R4/R5/R8/R9/R10 all failed to beat this structure — do not perturb.]
__device__ __forceinline__ void gru_chunk(
    const u16* __restrict__ gx, const u16* __restrict__ Whh, const float* __restrict__ bhh,
    u16* hbuf, unsigned* flags, u16* h1c, float* hstate, int base,
    int bl, u16* Ws, float* part, float* bsh)
{
  int tid = threadIdx.x, lane = tid & 63, w = tid >> 6;
  int g = bl >> 6, wg = bl & 63;
  int c0 = wg * 16, rb0 = g * 32;
  for (int ch = tid; ch < 48 * 128; ch += 256){
    int r = ch >> 7, o = ch & 127;
    const u16* src = Whh + (size_t)((r >> 4) * HH + c0 + (r & 15)) * HH + o * 8;
    *reinterpret_cast<int4*>(&Ws[r * 1032 + o * 8]) = *reinterpret_cast<const int4*>(src);
  }
  if (tid < 48) bsh[tid] = bhh[(tid >> 4) * HH + c0 + (tid & 15)];
  __syncthreads();
  int b2 = tid >> 4, j = tid & 15;
  int fr = lane & 15, klo = (lane >> 4) * 8, kw = w * 256;
  const u16* gxp0 = gx + (size_t)(rb0 + b2) * TC * GN + c0 + j;
  const u16* gxp1 = gx + (size_t)(rb0 + 16 + b2) * TC * GN + c0 + j;
  unsigned* fgrp = flags + g * 1024;           // 64 WGs x 16 u32 (64B padded)
  float ho0 = hstate[(size_t)(rb0 + b2) * HH + c0 + j];
  float ho1 = hstate[(size_t)(rb0 + 16 + b2) * HH + c0 + j];
  int lnD = (b2 >> 2) * 16 + j, regD = b2 & 3; // D map: col=lane&15,row=(lane>>4)*4+reg
  float br = bhh[c0 + j];
  for (int tl = 0; tl < TC; ++tl){
    int t = base + tl;
    // gx loads are h-independent — issue before the wait, overlap the poll
    float gxr0 = bf2f(gxp0[(size_t)tl * GN]);
    float gxz0 = bf2f(gxp0[(size_t)tl * GN + HH]);
    float gxn0 = bf2f(gxp0[(size_t)tl * GN + 2 * HH]);
    float gxr1 = bf2f(gxp1[(size_t)tl * GN]);
    float gxz1 = bf2f(gxp1[(size_t)tl * GN + HH]);
    float gxn1 = bf2f(gxp1[(size_t)tl * GN + 2 * HH]);
    if (tl){
      for (;;){
        unsigned v = __hip_atomic_load(fgrp + lane * 16, __ATOMIC_RELAXED,
                                       __HIP_MEMORY_SCOPE_AGENT);
        if (__all((int)(v >= (unsigned)tl))) break;
        __builtin_amdgcn_s_sleep(1);
      }
    }
    asm volatile("" ::: "memory");   // keep h loads below the poll
    // h loads: PLAIN CACHED 16B loads from the read slot (first-touch)
    const u16* rslot = hbuf + (size_t)(((t - 1) % 65) + 1) * (BB * HH);
    const u16* hr0 = rslot + (size_t)(rb0 + fr) * HH + kw + klo;
    const u16* hr1 = hr0 + (size_t)16 * HH;
    bf16x8 af0[8], af1[8];
    #pragma unroll
    for (int ks = 0; ks < 8; ++ks){
      af0[ks] = *reinterpret_cast<const bf16x8*>(hr0 + ks * 32);
      af1[ks] = *reinterpret_cast<const bf16x8*>(hr1 + ks * 32);
    }
    f32x4 acc[2][3] = {};
    #pragma unroll
    for (int ks = 0; ks < 8; ++ks){
      int kk = kw + ks * 32 + klo;
      bf16x8 w0 = *reinterpret_cast<const bf16x8*>(&Ws[(      fr) * 1032 + kk]);
      bf16x8 w1 = *reinterpret_cast<const bf16x8*>(&Ws[(16 + fr) * 1032 + kk]);
      bf16x8 w2 = *reinterpret_cast<const bf16x8*>(&Ws[(32 + fr) * 1032 + kk]);
      acc[0][0] = __builtin_amdgcn_mfma_f32_16x16x32_bf16(af0[ks], w0, acc[0][0], 0, 0, 0);
      acc[0][1] = __builtin_amdgcn_mfma_f32_16x16x32_bf16(af0[ks], w1, acc[0][1], 0, 0, 0);
      acc[0][2] = __builtin_amdgcn_mfma_f32_16x16x32_bf16(af0[ks], w2, acc[0][2], 0, 0, 0);
      acc[1][0] = __builtin_amdgcn_mfma_f32_16x16x32_bf16(af1[ks], w0, acc[1][0], 0, 0, 0);
      acc[1][1] = __builtin_amdgcn_mfma_f32_16x16x32_bf16(af1[ks], w1, acc[1][1], 0, 0, 0);
      acc[1][2] = __builtin_amdgcn_mfma_f32_16x16x32_bf16(af1[ks], w2, acc[1][2], 0, 0, 0);
    }
    #pragma unroll
    for (int at = 0; at < 2; ++at)
      #pragma unroll
      for (int gt = 0; gt < 3; ++gt)
        *reinterpret_cast<f32x4*>(&part[((w*6 + at*3 + gt)*64 + lane)*4]) = acc[at][gt];
    __syncthreads();
    float gh[2][3];
    #pragma unroll
    for (int at = 0; at < 2; ++at)
      #pragma unroll
      for (int gt = 0; gt < 3; ++gt){
        float s = 0.f;
        #pragma unroll
        for (int ww = 0; ww < 4; ++ww)
          s += part[((ww*6 + at*3 + gt)*64 + lnD)*4 + regD];
        gh[at][gt] = s;
      }
    float bz = bsh[16 + j], bn2 = bsh[32 + j];
    float r0 = __builtin_amdgcn_rcpf(1.f + __expf(-(gxr0 + gh[0][0] + br)));
    float z0 = __builtin_amdgcn_rcpf(1.f + __expf(-(gxz0 + gh[0][1] + bz)));
    float nx0 = gxn0 + r0 * (gh[0][2] + bn2);
    float n0 = 1.f - 2.f * __builtin_amdgcn_rcpf(__expf(2.f * nx0) + 1.f);
    float hn0 = (1.f - z0) * n0 + z0 * ho0;
    float r1 = __builtin_amdgcn_rcpf(1.f + __expf(-(gxr1 + gh[1][0] + br)));
    float z1 = __builtin_amdgcn_rcpf(1.f + __expf(-(gxz1 + gh[1][1] + bz)));
    float nx1 = gxn1 + r1 * (gh[1][2] + bn2);
    float n1 = 1.f - 2.f * __builtin_amdgcn_rcpf(__expf(2.f * nx1) + 1.f);
    float hn1 = (1.f - z1) * n1 + z1 * ho1;
    ho0 = hn0; ho1 = hn1;                        // f32 self-path
    u16 hb0 = f2bf(hn0), hb1 = f2bf(hn1);
    // h stores: device-scope write-through to LLC at the write slot
    u16* wslot = hbuf + (size_t)((t % 65) + 1) * (BB * HH);
    size_t d0 = (size_t)(rb0 + b2) * HH + c0 + j;
    __hip_atomic_store(wslot + d0,                hb0, __ATOMIC_RELAXED, __HIP_MEMORY_SCOPE_AGENT);
    __hip_atomic_store(wslot + d0 + (size_t)16*HH, hb1, __ATOMIC_RELAXED, __HIP_MEMORY_SCOPE_AGENT);
    if (h1c){
      h1c[((size_t)(rb0 + b2) * TC + tl) * HH + c0 + j] = hb0;
      h1c[((size_t)(rb0 + 16 + b2) * TC + tl) * HH + c0 + j] = hb1;
    }
    if (tl == TC - 1){
      hstate[(size_t)(rb0 + b2) * HH + c0 + j] = hn0;
      hstate[(size_t)(rb0 + 16 + b2) * HH + c0 + j] = hn1;
    }
    __syncthreads();   // vmcnt(0) drain of all WG h-stores before signaling
    if (tid == 0)
      __hip_atomic_store(fgrp + wg * 16, (unsigned)(tl + 1), __ATOMIC_RELAXED,
                         __HIP_MEMORY_SCOPE_AGENT);
  }
}

// --------- fused dispatch: 128 WGs role A (L0 chunk c) || 128 WGs role B (L1 chunk c-1)
__global__ __launch_bounds__(256, 1) void gru_fused(
    const u16* gxA, const u16* WhhA, const float* bhhA, u16* hbufA,
    unsigned* flA, u16* h1cA, float* hstA, int baseA,
    const u16* gxB, const u16* WhhB, const float* bhhB, u16* hbufB,
    unsigned* flB, float* hstB, int baseB)
{
  __shared__ u16 Ws[48 * 1032];      // 99KB
  __shared__ float part[4*6*64*4];   // 24KB
  __shared__ float bsh[48];
  int blk = blockIdx.x;
  if (blk < 128){
    if (!gxA) return;
    gru_chunk(gxA, WhhA, bhhA, hbufA, flA, h1cA, hstA, baseA, blk, Ws, part, bsh);
  } else {
    if (!gxB) return;
    gru_chunk(gxB, WhhB, bhhB, hbufB, flB, nullptr, hstB, baseB, blk - 128, Ws, part, bsh);
  }
}

// ---------------------------------------------------- x_projected[:, -1, :] (f32)
__global__ __launch_bounds__(256) void xproj_kernel(const float* __restrict__ x,
    const float* __restrict__ wproj, const float* __restrict__ bproj, float* __restrict__ xp){
  __shared__ float xs[II];
  int b = blockIdx.x >> 2, n0 = (blockIdx.x & 3) << 8;
  const float* xrow = x + ((size_t)b * TT + (TT - 1)) * II;
  for (int i = threadIdx.x; i < II; i += 256) xs[i] = xrow[i];
  __syncthreads();
  int n = n0 + threadIdx.x;
  const float* wrow = wproj + (size_t)n * II;
  float s = 0.f;
  #pragma unroll 4
  for (int k = 0; k < II; k += 4){
    float4 w4 = *reinterpret_cast<const float4*>(&wrow[k]);
    s += xs[k]*w4.x + xs[k+1]*w4.y + xs[k+2]*w4.z + xs[k+3]*w4.w;
  }
  xp[(size_t)b * HH + n] = s + bproj[n];
}

// ------------------------------------- residual + BN(inference) + out GEMM (f32)
__global__ __launch_bounds__(256) void final_kernel(const float* __restrict__ xp,
    const float* __restrict__ hl, const float* __restrict__ gamma, const float* __restrict__ beta,
    const float* __restrict__ mean, const float* __restrict__ var,
    const float* __restrict__ wout, const float* __restrict__ bout, float* __restrict__ out){
  __shared__ float bn[2 * HH];
  int b0 = blockIdx.x * 2;
  for (int i = threadIdx.x; i < 2 * HH; i += 256){
    int bb = i >> 10, jj = i & (HH - 1);
    float res = xp[(size_t)(b0 + bb) * HH + jj] + hl[(size_t)(b0 + bb) * HH + jj];
    bn[i] = (res - mean[jj]) * rsqrtf(var[jj] + 1e-5f) * gamma[jj] + beta[jj];
  }
  __syncthreads();
  int bb = threadIdx.x >> 7, o = threadIdx.x & (OO - 1);
  const float* wrow = wout + (size_t)o * HH;
  const float* bnrow = bn + bb * HH;
  float s = 0.f;
  #pragma unroll 4
  for (int k = 0; k < HH; k += 4){
    float4 w4 = *reinterpret_cast<const float4*>(&wrow[k]);
    s += bnrow[k]*w4.x + bnrow[k+1]*w4.y + bnrow[k+2]*w4.z + bnrow[k+3]*w4.w;
  }
  out[(size_t)(b0 + bb) * OO + o] = s + bout[o];
}

extern "C" void kernel_launch(void* const* d_in, const int* in_sizes, int n_in,
                              void* d_out, int out_size, void* d_ws, size_t ws_size,
                              hipStream_t stream) {
  const float* x      = (const float*)d_in[0];
  const float* w_proj = (const float*)d_in[1];
  const float* b_proj = (const float*)d_in[2];
  const float* w_ih0  = (const float*)d_in[3];
  const float* w_hh0  = (const float*)d_in[4];
  const float* b_ih0  = (const float*)d_in[5];
  const float* b_hh0  = (const float*)d_in[6];
  const float* w_ih1  = (const float*)d_in[7];
  const float* w_hh1  = (const float*)d_in[8];
  const float* b_ih1  = (const float*)d_in[9];
  const float* b_hh1  = (const float*)d_in[10];
  const float* gamma  = (const float*)d_in[11];
  const float* beta   = (const float*)d_in[12];
  const float* mean   = (const float*)d_in[13];
  const float* var    = (const float*)d_in[14];
  const float* w_out  = (const float*)d_in[15];
  const float* b_out  = (const float*)d_in[16];
  float* out = (float*)d_out;

  char* ws = (char*)d_ws;
  size_t off = 0;
  unsigned* flags = (unsigned*)(ws + off); off += (size_t)18 * 2048 * 4;   // 144 KB
  float* hst0  = (float*)(ws + off); off += (size_t)BB*HH*4;               // 256 KB
  float* hst1  = (float*)(ws + off); off += (size_t)BB*HH*4;
  size_t zeroA = off;                                                      // flags+hstates
  u16* hbuf0   = (u16*)(ws + off);   off += (size_t)NSLOT*BB*HH*2;         // 8.65 MB
  u16* hbuf1   = (u16*)(ws + off);   off += (size_t)NSLOT*BB*HH*2;
  float* xproj = (float*)(ws + off); off += (size_t)BB*HH*4;
  u16* xb      = (u16*)(ws + off);   off += (size_t)BB*TT*II*2;            // 33.5 MB
  u16* h1c     = (u16*)(ws + off);   off += (size_t)BB*TC*HH*2;            // 8.4 MB
  u16* wih0b   = (u16*)(ws + off);   off += (size_t)3*HH*II*2;             // 3.1 MB
  u16* whh0b   = (u16*)(ws + off);   off += (size_t)3*HH*HH*2;             // 6.3 MB
  u16* wih1b   = (u16*)(ws + off);   off += (size_t)3*HH*HH*2;
  u16* whh1b   = (u16*)(ws + off);   off += (size_t)3*HH*HH*2;
  u16* gxc0    = (u16*)(ws + off);   off += (size_t)BB*TC*3*HH*2;          // 25.2 MB
  u16* gxc1    = (u16*)(ws + off);   off += (size_t)BB*TC*3*HH*2;
  // total ~132 MB

  hipMemsetAsync(d_ws, 0, zeroA, stream);                    // flags + hstates
  hipMemsetAsync(hbuf0, 0, (size_t)BB*HH*2, stream);         // slot 0 = h(-1) = 0
  hipMemsetAsync(hbuf1, 0, (size_t)BB*HH*2, stream);

  cvt_kernel<<<512, 256, 0, stream>>>(w_ih0, wih0b, (3*HH*II) / 4);
  cvt_kernel<<<512, 256, 0, stream>>>(w_hh0, whh0b, (3*HH*HH) / 4);
  cvt_kernel<<<512, 256, 0, stream>>>(w_ih1, wih1b, (3*HH*HH) / 4);
  cvt_kernel<<<512, 256, 0, stream>>>(w_hh1, whh1b, (3*HH*HH) / 4);
  cvt_kernel<<<2048, 256, 0, stream>>>(x, xb, (BB*TT*II) / 4);   // full x -> bf16 once

  xproj_kernel<<<256, 256, 0, stream>>>(x, w_proj, b_proj, xproj);

  dim3 ggrid(BB * TC / 128, GN / 128);           // (32, 24)
  dim3 g2grid(BB * TC / 128, 2 * (GN / 128));    // (32, 48): gx1 + gx0 combined
  auto fl = [&](int k, int role){ return flags + (size_t)(k*2 + role) * 2048; };

  // prologue: gx0 chunk 0 (reads xb via XMAP row mapping)
  gemm_bias<II, true><<<ggrid, 256, 0, stream>>>(xb, wih0b, b_ih0, gxc0);
  gru_fused<<<256, 256, 0, stream>>>(gxc0, whh0b, b_hh0, hbuf0, fl(0,0), h1c, hst0, 0,
                                     nullptr, whh1b, b_hh1, hbuf1, fl(0,1), hst1, 0);
  // steady state: [gx1(k-1) + gx0(k)] one dispatch, then L0(k) || L1(k-1)
  for (int k = 1; k < NCH; ++k){
    gemm2<<<g2grid, 256, 0, stream>>>(h1c, wih1b, b_ih1, gxc1,
                                      xb + (size_t)k * TC * II, wih0b, b_ih0, gxc0);
    gru_fused<<<256, 256, 0, stream>>>(gxc0, whh0b, b_hh0, hbuf0, fl(k,0), h1c, hst0, k*TC,
                                       gxc1, whh1b, b_hh1, hbuf1, fl(k,1), hst1, (k-1)*TC);
  }
  // epilogue: L1 chunk 7 alone
  gemm_bias<HH, false><<<ggrid, 256, 0, stream>>>(h1c, wih1b, b_ih1, gxc1);
  gru_fused<<<256, 256, 0, stream>>>(nullptr, whh0b, b_hh0, hbuf0, fl(8,0), h1c, hst0, 0,
                                     gxc1, whh1b, b_hh1, hbuf1, fl(8,1), hst1, (NCH-1)*TC);

  final_kernel<<<BB / 2, 256, 0, stream>>>(xproj, hst1, gamma, beta, mean, var, w_out, b_out, out);
}

// Round 12
// 3063.576 us; speedup vs baseline: 1.7244x; 1.0830x over previous
//
#include <hip/hip_runtime.h>
#include <math.h>

// Problem constants
#define BB 64
#define TT 512
#define II 512
#define HH 1024
#define OO 128
#define GN (3*HH)       // 3072
#define TC 64           // time chunk
#define NCH (TT/TC)     // 8 chunks
#define NSLOT 66        // rolling h slots: slot 0 = initial zeros, 1..65 rotate

using u16 = unsigned short;
typedef __attribute__((ext_vector_type(8))) short bf16x8;
typedef __attribute__((ext_vector_type(4))) float f32x4;
typedef __attribute__((ext_vector_type(4))) unsigned short u16x4;

__device__ __forceinline__ u16 f2bf(float f){
  unsigned u = __builtin_bit_cast(unsigned, f);
  u += 0x7fffu + ((u >> 16) & 1u);          // RNE
  return (u16)(u >> 16);
}
__device__ __forceinline__ float bf2f(u16 h){
  unsigned u = ((unsigned)h) << 16;
  return __builtin_bit_cast(float, u);
}

// ---------------------------------------------------------------- f32 -> bf16
__global__ __launch_bounds__(256) void cvt_kernel(const float* __restrict__ s,
                                                  u16* __restrict__ d, int n4){
  int stride = gridDim.x * 256;
  for (int i = blockIdx.x * 256 + threadIdx.x; i < n4; i += stride){
    float4 v = reinterpret_cast<const float4*>(s)[i];
    u16x4 o; o.x = f2bf(v.x); o.y = f2bf(v.y); o.z = f2bf(v.z); o.w = f2bf(v.w);
    reinterpret_cast<u16x4*>(d)[i] = o;
  }
}

// ------------------------------------------------- bf16 GEMM (m97 structure)
// C = A@Bw^T + bias, 128x128 tile, BK=32, 4 waves, global_load_lds width 16.
// XMAP=true: A rows map through full-sequence layout [B,TT,K]:
// chunk-row r -> (r>>6)*TT + (r&63); caller offsets A by k*TC rows.
template<int K, bool XMAP>
__global__ __launch_bounds__(256) void gemm_bias(const u16* __restrict__ A,
    const u16* __restrict__ Bw, const float* __restrict__ bias, u16* __restrict__ C){
  __shared__ u16 As[128*32];
  __shared__ u16 Bs[128*32];
  int tid = threadIdx.x;
  int lane = tid & 63, wave = tid >> 6;
  int m0 = blockIdx.x * 128, n0 = blockIdx.y * 128;
  int wr = (wave >> 1) * 64, wc = (wave & 1) * 64;
  int fr = lane & 15, fo = (lane >> 4) * 8;
  f32x4 acc[4][4] = {};
  for (int k0 = 0; k0 < K; k0 += 32){
    __syncthreads();
    #pragma unroll
    for (int c = 0; c < 2; ++c){
      int chunk = wave * 2 + c;
      int s = chunk * 64 + lane;
      int row = s >> 2, o = s & 3;
      int ar = m0 + row;
      size_t aoff = XMAP ? ((size_t)(ar >> 6) * TT + (ar & 63)) * K
                         : (size_t)ar * K;
      const u16* ga = A  + aoff + k0 + o * 8;
      const u16* gb = Bw + (size_t)(n0 + row) * K + k0 + o * 8;
      __builtin_amdgcn_global_load_lds(
          (const __attribute__((address_space(1))) unsigned int*)ga,
          (__attribute__((address_space(3))) unsigned int*)(As + chunk * 512), 16, 0, 0);
      __builtin_amdgcn_global_load_lds(
          (const __attribute__((address_space(1))) unsigned int*)gb,
          (__attribute__((address_space(3))) unsigned int*)(Bs + chunk * 512), 16, 0, 0);
    }
    __syncthreads();
    bf16x8 af[4], bf[4];
    #pragma unroll
    for (int m = 0; m < 4; ++m)
      af[m] = *reinterpret_cast<const bf16x8*>(&As[(wr + m*16 + fr) * 32 + fo]);
    #pragma unroll
    for (int n = 0; n < 4; ++n)
      bf[n] = *reinterpret_cast<const bf16x8*>(&Bs[(wc + n*16 + fr) * 32 + fo]);
    #pragma unroll
    for (int m = 0; m < 4; ++m)
      #pragma unroll
      for (int n = 0; n < 4; ++n)
        acc[m][n] = __builtin_amdgcn_mfma_f32_16x16x32_bf16(af[m], bf[n], acc[m][n], 0, 0, 0);
  }
  int r4 = (lane >> 4) * 4;
  #pragma unroll
  for (int n = 0; n < 4; ++n){
    int col = n0 + wc + n*16 + fr;
    float bv = bias[col];
    #pragma unroll
    for (int m = 0; m < 4; ++m){
      #pragma unroll
      for (int q = 0; q < 4; ++q){
        int row = m0 + wr + m*16 + r4 + q;
        C[(size_t)row * GN + col] = f2bf(acc[m][n][q] + bv);
      }
    }
  }
}

// --------------------------------------------------- GRU chunk body (R7, proven)
// Per role: 128 WGs = 2 batch-groups(32 rows) x 64 col-slices(16 cols).
// W slice in LDS; rolling 66-slot hbuf; producer relaxed agent atomic 2B stores +
// WG __syncthreads (vmcnt drain) + per-WG flag; consumer polls 64 flags (1/lane),
// then PLAIN CACHED 16B h loads (first-touch per dispatch). [R7: 295us/dispatch;
// R4/R5/R8/R9/R10 all failed to beat this structure — do not perturb.]
__device__ __forceinline__ void gru_chunk(
    const u16* __restrict__ gx, const u16* __restrict__ Whh, const float* __restrict__ bhh,
    u16* hbuf, unsigned* flags, u16* h1c, float* hstate, int base,
    int bl, u16* Ws, float* part, float* bsh)
{
  int tid = threadIdx.x, lane = tid & 63, w = tid >> 6;
  int g = bl >> 6, wg = bl & 63;
  int c0 = wg * 16, rb0 = g * 32;
  for (int ch = tid; ch < 48 * 128; ch += 256){
    int r = ch >> 7, o = ch & 127;
    const u16* src = Whh + (size_t)((r >> 4) * HH + c0 + (r & 15)) * HH + o * 8;
    *reinterpret_cast<int4*>(&Ws[r * 1032 + o * 8]) = *reinterpret_cast<const int4*>(src);
  }
  if (tid < 48) bsh[tid] = bhh[(tid >> 4) * HH + c0 + (tid & 15)];
  __syncthreads();
  int b2 = tid >> 4, j = tid & 15;
  int fr = lane & 15, klo = (lane >> 4) * 8, kw = w * 256;
  const u16* gxp0 = gx + (size_t)(rb0 + b2) * TC * GN + c0 + j;
  const u16* gxp1 = gx + (size_t)(rb0 + 16 + b2) * TC * GN + c0 + j;
  unsigned* fgrp = flags + g * 1024;           // 64 WGs x 16 u32 (64B padded)
  float ho0 = hstate[(size_t)(rb0 + b2) * HH + c0 + j];
  float ho1 = hstate[(size_t)(rb0 + 16 + b2) * HH + c0 + j];
  int lnD = (b2 >> 2) * 16 + j, regD = b2 & 3; // D map: col=lane&15,row=(lane>>4)*4+reg
  float br = bhh[c0 + j];
  for (int tl = 0; tl < TC; ++tl){
    int t = base + tl;
    // gx loads are h-independent — issue before the wait, overlap the poll
    float gxr0 = bf2f(gxp0[(size_t)tl * GN]);
    float gxz0 = bf2f(gxp0[(size_t)tl * GN + HH]);
    float gxn0 = bf2f(gxp0[(size_t)tl * GN + 2 * HH]);
    float gxr1 = bf2f(gxp1[(size_t)tl * GN]);
    float gxz1 = bf2f(gxp1[(size_t)tl * GN + HH]);
    float gxn1 = bf2f(gxp1[(size_t)tl * GN + 2 * HH]);
    if (tl){
      for (;;){
        unsigned v = __hip_atomic_load(fgrp + lane * 16, __ATOMIC_RELAXED,
                                       __HIP_MEMORY_SCOPE_AGENT);
        if (__all((int)(v >= (unsigned)tl))) break;
        __builtin_amdgcn_s_sleep(1);
      }
    }
    asm volatile("" ::: "memory");   // keep h loads below the poll
    // h loads: PLAIN CACHED 16B loads from the read slot (first-touch)
    const u16* rslot = hbuf + (size_t)(((t - 1) % 65) + 1) * (BB * HH);
    const u16* hr0 = rslot + (size_t)(rb0 + fr) * HH + kw + klo;
    const u16* hr1 = hr0 + (size_t)16 * HH;
    bf16x8 af0[8], af1[8];
    #pragma unroll
    for (int ks = 0; ks < 8; ++ks){
      af0[ks] = *reinterpret_cast<const bf16x8*>(hr0 + ks * 32);
      af1[ks] = *reinterpret_cast<const bf16x8*>(hr1 + ks * 32);
    }
    f32x4 acc[2][3] = {};
    #pragma unroll
    for (int ks = 0; ks < 8; ++ks){
      int kk = kw + ks * 32 + klo;
      bf16x8 w0 = *reinterpret_cast<const bf16x8*>(&Ws[(      fr) * 1032 + kk]);
      bf16x8 w1 = *reinterpret_cast<const bf16x8*>(&Ws[(16 + fr) * 1032 + kk]);
      bf16x8 w2 = *reinterpret_cast<const bf16x8*>(&Ws[(32 + fr) * 1032 + kk]);
      acc[0][0] = __builtin_amdgcn_mfma_f32_16x16x32_bf16(af0[ks], w0, acc[0][0], 0, 0, 0);
      acc[0][1] = __builtin_amdgcn_mfma_f32_16x16x32_bf16(af0[ks], w1, acc[0][1], 0, 0, 0);
      acc[0][2] = __builtin_amdgcn_mfma_f32_16x16x32_bf16(af0[ks], w2, acc[0][2], 0, 0, 0);
      acc[1][0] = __builtin_amdgcn_mfma_f32_16x16x32_bf16(af1[ks], w0, acc[1][0], 0, 0, 0);
      acc[1][1] = __builtin_amdgcn_mfma_f32_16x16x32_bf16(af1[ks], w1, acc[1][1], 0, 0, 0);
      acc[1][2] = __builtin_amdgcn_mfma_f32_16x16x32_bf16(af1[ks], w2, acc[1][2], 0, 0, 0);
    }
    #pragma unroll
    for (int at = 0; at < 2; ++at)
      #pragma unroll
      for (int gt = 0; gt < 3; ++gt)
        *reinterpret_cast<f32x4*>(&part[((w*6 + at*3 + gt)*64 + lane)*4]) = acc[at][gt];
    __syncthreads();
    float gh[2][3];
    #pragma unroll
    for (int at = 0; at < 2; ++at)
      #pragma unroll
      for (int gt = 0; gt < 3; ++gt){
        float s = 0.f;
        #pragma unroll
        for (int ww = 0; ww < 4; ++ww)
          s += part[((ww*6 + at*3 + gt)*64 + lnD)*4 + regD];
        gh[at][gt] = s;
      }
    float bz = bsh[16 + j], bn2 = bsh[32 + j];
    float r0 = __builtin_amdgcn_rcpf(1.f + __expf(-(gxr0 + gh[0][0] + br)));
    float z0 = __builtin_amdgcn_rcpf(1.f + __expf(-(gxz0 + gh[0][1] + bz)));
    float nx0 = gxn0 + r0 * (gh[0][2] + bn2);
    float n0 = 1.f - 2.f * __builtin_amdgcn_rcpf(__expf(2.f * nx0) + 1.f);
    float hn0 = (1.f - z0) * n0 + z0 * ho0;
    float r1 = __builtin_amdgcn_rcpf(1.f + __expf(-(gxr1 + gh[1][0] + br)));
    float z1 = __builtin_amdgcn_rcpf(1.f + __expf(-(gxz1 + gh[1][1] + bz)));
    float nx1 = gxn1 + r1 * (gh[1][2] + bn2);
    float n1 = 1.f - 2.f * __builtin_amdgcn_rcpf(__expf(2.f * nx1) + 1.f);
    float hn1 = (1.f - z1) * n1 + z1 * ho1;
    ho0 = hn0; ho1 = hn1;                        // f32 self-path
    u16 hb0 = f2bf(hn0), hb1 = f2bf(hn1);
    // h stores: device-scope write-through to LLC at the write slot
    u16* wslot = hbuf + (size_t)((t % 65) + 1) * (BB * HH);
    size_t d0 = (size_t)(rb0 + b2) * HH + c0 + j;
    __hip_atomic_store(wslot + d0,                hb0, __ATOMIC_RELAXED, __HIP_MEMORY_SCOPE_AGENT);
    __hip_atomic_store(wslot + d0 + (size_t)16*HH, hb1, __ATOMIC_RELAXED, __HIP_MEMORY_SCOPE_AGENT);
    if (h1c){
      h1c[((size_t)(rb0 + b2) * TC + tl) * HH + c0 + j] = hb0;
      h1c[((size_t)(rb0 + 16 + b2) * TC + tl) * HH + c0 + j] = hb1;
    }
    if (tl == TC - 1){
      hstate[(size_t)(rb0 + b2) * HH + c0 + j] = hn0;
      hstate[(size_t)(rb0 + 16 + b2) * HH + c0 + j] = hn1;
    }
    __syncthreads();   // vmcnt(0) drain of all WG h-stores before signaling
    if (tid == 0)
      __hip_atomic_store(fgrp + wg * 16, (unsigned)(tl + 1), __ATOMIC_RELAXED,
                         __HIP_MEMORY_SCOPE_AGENT);
  }
}

// --------- fused dispatch: 128 WGs role A (L0 chunk c) || 128 WGs role B (L1 chunk c-1)
__global__ __launch_bounds__(256, 1) void gru_fused(
    const u16* gxA, const u16* WhhA, const float* bhhA, u16* hbufA,
    unsigned* flA, u16* h1cA, float* hstA, int baseA,
    const u16* gxB, const u16* WhhB, const float* bhhB, u16* hbufB,
    unsigned* flB, float* hstB, int baseB)
{
  __shared__ u16 Ws[48 * 1032];      // 99KB
  __shared__ float part[4*6*64*4];   // 24KB
  __shared__ float bsh[48];
  int blk = blockIdx.x;
  if (blk < 128){
    if (!gxA) return;
    gru_chunk(gxA, WhhA, bhhA, hbufA, flA, h1cA, hstA, baseA, blk, Ws, part, bsh);
  } else {
    if (!gxB) return;
    gru_chunk(gxB, WhhB, bhhB, hbufB, flB, nullptr, hstB, baseB, blk - 128, Ws, part, bsh);
  }
}

// ---------------------------------------------------- x_projected[:, -1, :] (f32)
__global__ __launch_bounds__(256) void xproj_kernel(const float* __restrict__ x,
    const float* __restrict__ wproj, const float* __restrict__ bproj, float* __restrict__ xp){
  __shared__ float xs[II];
  int b = blockIdx.x >> 2, n0 = (blockIdx.x & 3) << 8;
  const float* xrow = x + ((size_t)b * TT + (TT - 1)) * II;
  for (int i = threadIdx.x; i < II; i += 256) xs[i] = xrow[i];
  __syncthreads();
  int n = n0 + threadIdx.x;
  const float* wrow = wproj + (size_t)n * II;
  float s = 0.f;
  #pragma unroll 4
  for (int k = 0; k < II; k += 4){
    float4 w4 = *reinterpret_cast<const float4*>(&wrow[k]);
    s += xs[k]*w4.x + xs[k+1]*w4.y + xs[k+2]*w4.z + xs[k+3]*w4.w;
  }
  xp[(size_t)b * HH + n] = s + bproj[n];
}

// ------------------------------------- residual + BN(inference) + out GEMM (f32)
__global__ __launch_bounds__(256) void final_kernel(const float* __restrict__ xp,
    const float* __restrict__ hl, const float* __restrict__ gamma, const float* __restrict__ beta,
    const float* __restrict__ mean, const float* __restrict__ var,
    const float* __restrict__ wout, const float* __restrict__ bout, float* __restrict__ out){
  __shared__ float bn[2 * HH];
  int b0 = blockIdx.x * 2;
  for (int i = threadIdx.x; i < 2 * HH; i += 256){
    int bb = i >> 10, jj = i & (HH - 1);
    float res = xp[(size_t)(b0 + bb) * HH + jj] + hl[(size_t)(b0 + bb) * HH + jj];
    bn[i] = (res - mean[jj]) * rsqrtf(var[jj] + 1e-5f) * gamma[jj] + beta[jj];
  }
  __syncthreads();
  int bb = threadIdx.x >> 7, o = threadIdx.x & (OO - 1);
  const float* wrow = wout + (size_t)o * HH;
  const float* bnrow = bn + bb * HH;
  float s = 0.f;
  #pragma unroll 4
  for (int k = 0; k < HH; k += 4){
    float4 w4 = *reinterpret_cast<const float4*>(&wrow[k]);
    s += bnrow[k]*w4.x + bnrow[k+1]*w4.y + bnrow[k+2]*w4.z + bnrow[k+3]*w4.w;
  }
  out[(size_t)(b0 + bb) * OO + o] = s + bout[o];
}

extern "C" void kernel_launch(void* const* d_in, const int* in_sizes, int n_in,
                              void* d_out, int out_size, void* d_ws, size_t ws_size,
                              hipStream_t stream) {
  const float* x      = (const float*)d_in[0];
  const float* w_proj = (const float*)d_in[1];
  const float* b_proj = (const float*)d_in[2];
  const float* w_ih0  = (const float*)d_in[3];
  const float* w_hh0  = (const float*)d_in[4];
  const float* b_ih0  = (const float*)d_in[5];
  const float* b_hh0  = (const float*)d_in[6];
  const float* w_ih1  = (const float*)d_in[7];
  const float* w_hh1  = (const float*)d_in[8];
  const float* b_ih1  = (const float*)d_in[9];
  const float* b_hh1  = (const float*)d_in[10];
  const float* gamma  = (const float*)d_in[11];
  const float* beta   = (const float*)d_in[12];
  const float* mean   = (const float*)d_in[13];
  const float* var    = (const float*)d_in[14];
  const float* w_out  = (const float*)d_in[15];
  const float* b_out  = (const float*)d_in[16];
  float* out = (float*)d_out;

  char* ws = (char*)d_ws;
  size_t off = 0;
  unsigned* flags = (unsigned*)(ws + off); off += (size_t)18 * 2048 * 4;   // 144 KB
  float* hst0  = (float*)(ws + off); off += (size_t)BB*HH*4;               // 256 KB
  float* hst1  = (float*)(ws + off); off += (size_t)BB*HH*4;
  size_t zeroA = off;                                                      // flags+hstates
  u16* hbuf0   = (u16*)(ws + off);   off += (size_t)NSLOT*BB*HH*2;         // 8.65 MB
  u16* hbuf1   = (u16*)(ws + off);   off += (size_t)NSLOT*BB*HH*2;
  float* xproj = (float*)(ws + off); off += (size_t)BB*HH*4;
  u16* xb      = (u16*)(ws + off);   off += (size_t)BB*TT*II*2;            // 33.5 MB
  u16* h1c     = (u16*)(ws + off);   off += (size_t)BB*TC*HH*2;            // 8.4 MB
  u16* wih0b   = (u16*)(ws + off);   off += (size_t)3*HH*II*2;             // 3.1 MB
  u16* whh0b   = (u16*)(ws + off);   off += (size_t)3*HH*HH*2;             // 6.3 MB
  u16* wih1b   = (u16*)(ws + off);   off += (size_t)3*HH*HH*2;
  u16* whh1b   = (u16*)(ws + off);   off += (size_t)3*HH*HH*2;
  u16* gxc0    = (u16*)(ws + off);   off += (size_t)BB*TC*3*HH*2;          // 25.2 MB
  u16* gxc1    = (u16*)(ws + off);   off += (size_t)BB*TC*3*HH*2;
  // total ~132 MB

  hipMemsetAsync(d_ws, 0, zeroA, stream);                    // flags + hstates
  hipMemsetAsync(hbuf0, 0, (size_t)BB*HH*2, stream);         // slot 0 = h(-1) = 0
  hipMemsetAsync(hbuf1, 0, (size_t)BB*HH*2, stream);

  cvt_kernel<<<512, 256, 0, stream>>>(w_ih0, wih0b, (3*HH*II) / 4);
  cvt_kernel<<<512, 256, 0, stream>>>(w_hh0, whh0b, (3*HH*HH) / 4);
  cvt_kernel<<<512, 256, 0, stream>>>(w_ih1, wih1b, (3*HH*HH) / 4);
  cvt_kernel<<<512, 256, 0, stream>>>(w_hh1, whh1b, (3*HH*HH) / 4);
  cvt_kernel<<<2048, 256, 0, stream>>>(x, xb, (BB*TT*II) / 4);   // full x -> bf16 once

  xproj_kernel<<<256, 256, 0, stream>>>(x, w_proj, b_proj, xproj);

  dim3 ggrid(BB * TC / 128, GN / 128);           // (32, 24)
  auto fl = [&](int k, int role){ return flags + (size_t)(k*2 + role) * 2048; };

  // prologue: gx0 chunk 0 (reads xb via XMAP row mapping)
  gemm_bias<II, true><<<ggrid, 256, 0, stream>>>(xb, wih0b, b_ih0, gxc0);
  gru_fused<<<256, 256, 0, stream>>>(gxc0, whh0b, b_hh0, hbuf0, fl(0,0), h1c, hst0, 0,
                                     nullptr, whh1b, b_hh1, hbuf1, fl(0,1), hst1, 0);
  // steady state: gx1(k-1), gx0(k) as separate dispatches (R11's merged gemm2
  // regressed ~36us/iter — do not merge), then L0(k) || L1(k-1)
  for (int k = 1; k < NCH; ++k){
    gemm_bias<HH, false><<<ggrid, 256, 0, stream>>>(h1c, wih1b, b_ih1, gxc1);
    gemm_bias<II, true ><<<ggrid, 256, 0, stream>>>(xb + (size_t)k * TC * II,
                                                    wih0b, b_ih0, gxc0);
    gru_fused<<<256, 256, 0, stream>>>(gxc0, whh0b, b_hh0, hbuf0, fl(k,0), h1c, hst0, k*TC,
                                       gxc1, whh1b, b_hh1, hbuf1, fl(k,1), hst1, (k-1)*TC);
  }
  // epilogue: L1 chunk 7 alone
  gemm_bias<HH, false><<<ggrid, 256, 0, stream>>>(h1c, wih1b, b_ih1, gxc1);
  gru_fused<<<256, 256, 0, stream>>>(nullptr, whh0b, b_hh0, hbuf0, fl(8,0), h1c, hst0, 0,
                                     gxc1, whh1b, b_hh1, hbuf1, fl(8,1), hst1, (NCH-1)*TC);

  final_kernel<<<BB / 2, 256, 0, stream>>>(xproj, hst1, gamma, beta, mean, var, w_out, b_out, out);
}